// Round 1
// baseline (335.278 us; speedup 1.0000x reference)
//
#include <hip/hip_runtime.h>
#include <hip/hip_bf16.h>

// Causal self-attention forward, B=4 S=2048 H=16 D=64, fp32 in/out, bf16 MFMA.
// qkv: (B,S,3,H,D) f32.  out: (B,H,S,D) f32.

#define S_LEN 2048
#define NHEAD 16
#define DHEAD 64
#define QBLK  64
#define KVBLK 32
#define SROW  3072   // s-stride in floats = 3*NHEAD*DHEAD
#define KOFF  1024   // offset of K within an s-row (floats)
#define VOFF  2048   // offset of V

#define KP 72   // K LDS row pitch (shorts): 144B rows -> 2-way (free) b128 reads
#define VP 40   // Vt LDS row pitch: 80B rows -> 2-way free
#define PP 40   // P LDS row pitch

typedef __attribute__((ext_vector_type(8))) short bf16x8;
typedef __attribute__((ext_vector_type(4))) float f32x4;

__device__ __forceinline__ short f2bf(float f) {
    union { __hip_bfloat16 b; short s; } u;
    u.b = __float2bfloat16(f);
    return u.s;
}

__global__ __launch_bounds__(256)
void attn_fwd_kernel(const float* __restrict__ qkv, float* __restrict__ out)
{
    __shared__ __attribute__((aligned(16))) short lds_k [KVBLK * KP];   // 4.6 KB
    __shared__ __attribute__((aligned(16))) short lds_vt[DHEAD * VP];   // 5.1 KB (V transposed: Vt[d][k])
    __shared__ __attribute__((aligned(16))) short lds_p [4 * 16 * PP];  // 5.1 KB (per-wave 16x32 P)

    const int tid  = threadIdx.x;
    const int wave = tid >> 6;
    const int lane = tid & 63;
    const int l16  = lane & 15;
    const int lg   = lane >> 4;          // 0..3

    const int bid = blockIdx.x;
    const int qb  = bid & 31;            // S/QBLK = 32
    const int bh  = bid >> 5;            // 0..63
    const int b   = bh >> 4;
    const int h   = bh & 15;

    const float* qkv_bh = qkv + (size_t)b * (S_LEN * SROW) + h * DHEAD;
    const int q0     = qb * QBLK;
    const int qrowA  = q0 + wave * 16 + l16;      // this lane's A-fragment q row
    const int qrowD0 = q0 + wave * 16 + lg * 4;   // D-layout row base (add r)

    // ---- Q fragments (pre-scaled by 1/sqrt(D) = 0.125 exact) ----
    bf16x8 qf[2];
    #pragma unroll
    for (int ks = 0; ks < 2; ++ks) {
        const float* qp = qkv_bh + (size_t)qrowA * SROW + ks * 32 + lg * 8;
        f32x4 a = *(const f32x4*)qp;
        f32x4 c = *(const f32x4*)(qp + 4);
        bf16x8 v;
        #pragma unroll
        for (int j = 0; j < 4; ++j) { v[j] = f2bf(a[j] * 0.125f); v[4 + j] = f2bf(c[j] * 0.125f); }
        qf[ks] = v;
    }

    // ---- flash state ----
    f32x4 o[4];
    float m_r[4], l_r[4];
    #pragma unroll
    for (int n = 0; n < 4; ++n) o[n] = (f32x4){0.f, 0.f, 0.f, 0.f};
    #pragma unroll
    for (int r = 0; r < 4; ++r) { m_r[r] = -1e30f; l_r[r] = 0.f; }

    // staging maps
    const int st_krow = tid >> 3;          // 0..31  (K row)
    const int st_dk   = (tid & 7) * 8;     // K d-base (8 elems -> one b128)
    const int st_p    = tid & 15;          // Vt: k-pair index (k = 2p, 2p+1)
    const int st_dv   = (tid >> 4) * 4;    // Vt: d-base (4 rows)

    const int ntiles = (q0 + QBLK) / KVBLK;
    for (int it = 0; it < ntiles; ++it) {
        const int kv0 = it * KVBLK;

        // ---- stage K tile [32][64] -> lds_k row-major ----
        {
            const float* kp = qkv_bh + (size_t)(kv0 + st_krow) * SROW + KOFF + st_dk;
            f32x4 a = *(const f32x4*)kp;
            f32x4 c = *(const f32x4*)(kp + 4);
            bf16x8 v;
            #pragma unroll
            for (int j = 0; j < 4; ++j) { v[j] = f2bf(a[j]); v[4 + j] = f2bf(c[j]); }
            *(bf16x8*)&lds_k[st_krow * KP + st_dk] = v;
        }
        // ---- stage V tile transposed: Vt[d][k] ----
        {
            const float* vp = qkv_bh + (size_t)(kv0 + 2 * st_p) * SROW + VOFF + st_dv;
            f32x4 a = *(const f32x4*)vp;
            f32x4 c = *(const f32x4*)(vp + SROW);
            #pragma unroll
            for (int i = 0; i < 4; ++i) {
                unsigned int lo = (unsigned short)f2bf(a[i]);
                unsigned int hi = (unsigned short)f2bf(c[i]);
                *(unsigned int*)&lds_vt[(st_dv + i) * VP + 2 * st_p] = lo | (hi << 16);
            }
        }
        __syncthreads();

        const bool skip = kv0 > q0 + wave * 16 + 15;   // tile fully above diagonal for this wave
        if (!skip) {
            // ---- S = Q K^T (two 16-col tiles) ----
            f32x4 s0 = (f32x4){0.f,0.f,0.f,0.f};
            f32x4 s1 = (f32x4){0.f,0.f,0.f,0.f};
            #pragma unroll
            for (int ks = 0; ks < 2; ++ks) {
                bf16x8 k0 = *(const bf16x8*)&lds_k[l16 * KP + ks * 32 + lg * 8];
                bf16x8 k1 = *(const bf16x8*)&lds_k[(16 + l16) * KP + ks * 32 + lg * 8];
                s0 = __builtin_amdgcn_mfma_f32_16x16x32_bf16(qf[ks], k0, s0, 0, 0, 0);
                s1 = __builtin_amdgcn_mfma_f32_16x16x32_bf16(qf[ks], k1, s1, 0, 0, 0);
            }
            // ---- causal mask (D layout: row = lg*4+r, col = l16) ----
            if (kv0 + KVBLK - 1 > q0 + wave * 16) {
                #pragma unroll
                for (int r = 0; r < 4; ++r) {
                    const int qg = qrowD0 + r;
                    if (kv0 + l16 > qg)      s0[r] = -1e30f;
                    if (kv0 + 16 + l16 > qg) s1[r] = -1e30f;
                }
            }
            // ---- online softmax ----
            #pragma unroll
            for (int r = 0; r < 4; ++r) {
                float mt = fmaxf(s0[r], s1[r]);
                mt = fmaxf(mt, __shfl_xor(mt, 1));
                mt = fmaxf(mt, __shfl_xor(mt, 2));
                mt = fmaxf(mt, __shfl_xor(mt, 4));
                mt = fmaxf(mt, __shfl_xor(mt, 8));
                const float mn    = fmaxf(m_r[r], mt);
                const float alpha = __expf(m_r[r] - mn);
                m_r[r] = mn;
                const float p0 = __expf(s0[r] - mn);
                const float p1 = __expf(s1[r] - mn);
                float rs = p0 + p1;
                rs += __shfl_xor(rs, 1);
                rs += __shfl_xor(rs, 2);
                rs += __shfl_xor(rs, 4);
                rs += __shfl_xor(rs, 8);
                l_r[r] = l_r[r] * alpha + rs;
                #pragma unroll
                for (int n = 0; n < 4; ++n) o[n][r] *= alpha;
                // P -> LDS (row-major [16][32], D-layout write)
                lds_p[(wave * 16 + lg * 4 + r) * PP + l16]      = f2bf(p0);
                lds_p[(wave * 16 + lg * 4 + r) * PP + 16 + l16] = f2bf(p1);
            }
            // ensure all lanes' P writes are visible before cross-lane fragment read
            asm volatile("s_waitcnt lgkmcnt(0)" ::: "memory");
            // ---- O += P V ----
            bf16x8 pa = *(const bf16x8*)&lds_p[(wave * 16 + l16) * PP + lg * 8];
            #pragma unroll
            for (int n = 0; n < 4; ++n) {
                bf16x8 vf = *(const bf16x8*)&lds_vt[(n * 16 + l16) * VP + lg * 8];
                o[n] = __builtin_amdgcn_mfma_f32_16x16x32_bf16(pa, vf, o[n], 0, 0, 0);
            }
        }
        __syncthreads();
    }

    // ---- epilogue: normalize and store (out is (B,H,S,D) f32) ----
    float* outp = out + ((size_t)bh * S_LEN + q0 + wave * 16) * DHEAD;
    #pragma unroll
    for (int r = 0; r < 4; ++r) {
        const float inv = 1.0f / l_r[r];
        #pragma unroll
        for (int n = 0; n < 4; ++n) {
            outp[(lg * 4 + r) * DHEAD + n * 16 + l16] = o[n][r] * inv;
        }
    }
}

extern "C" void kernel_launch(void* const* d_in, const int* in_sizes, int n_in,
                              void* d_out, int out_size, void* d_ws, size_t ws_size,
                              hipStream_t stream) {
    const float* qkv = (const float*)d_in[0];
    float* out = (float*)d_out;
    const int nblocks = (S_LEN / QBLK) * 4 * NHEAD;   // 32 * 64 = 2048
    attn_fwd_kernel<<<dim3(nblocks), dim3(256), 0, stream>>>(qkv, out);
}

// Round 2
// 234.055 us; speedup vs baseline: 1.4325x; 1.4325x over previous
//
#include <hip/hip_runtime.h>
#include <hip/hip_bf16.h>

// Causal self-attention forward, B=4 S=2048 H=16 D=64, fp32 in/out, bf16 MFMA.
// qkv: (B,S,3,H,D) f32.  out: (B,H,S,D) f32.
// Round 1: QBLK=128 (32 q-rows/wave), KVBLK=64, T14 prefetch (reg-staged next
// tile issued under compute), reversed qb order (deep blocks first).

#define S_LEN 2048
#define NHEAD 16
#define DHEAD 64
#define QBLK  128
#define KVBLK 64
#define SROW  3072   // s-stride in floats = 3*NHEAD*DHEAD
#define KOFF  1024   // K offset within an s-row (floats)
#define VOFF  2048   // V offset

#define KP 72   // K LDS pitch (shorts)
#define VP 72   // Vt LDS pitch
#define PP 72   // P LDS pitch

typedef __attribute__((ext_vector_type(8))) short bf16x8;
typedef __attribute__((ext_vector_type(4))) float f32x4;

__device__ __forceinline__ short f2bf(float f) {
    union { __hip_bfloat16 b; short s; } u;
    u.b = __float2bfloat16(f);
    return u.s;
}
__device__ __forceinline__ unsigned int pack2(float lo, float hi) {
    return (unsigned int)(unsigned short)f2bf(lo) | ((unsigned int)(unsigned short)f2bf(hi) << 16);
}

__global__ __launch_bounds__(256)
void attn_fwd_kernel(const float* __restrict__ qkv, float* __restrict__ out)
{
    __shared__ __attribute__((aligned(16))) short lds_k [KVBLK * KP];   // 9.2 KB
    __shared__ __attribute__((aligned(16))) short lds_vt[DHEAD * VP];   // 9.2 KB (V transposed)
    __shared__ __attribute__((aligned(16))) short lds_p [4 * 32 * PP];  // 18.4 KB

    const int tid  = threadIdx.x;
    const int wave = tid >> 6;
    const int lane = tid & 63;
    const int l16  = lane & 15;
    const int lg   = lane >> 4;

    const int bid = blockIdx.x;
    const int qb  = 15 - (bid & 15);     // deepest q-blocks get lowest blockIdx
    const int bh  = bid >> 4;            // 0..63

    const float* qkv_bh = qkv + (size_t)(bh >> 4) * (S_LEN * SROW) + (bh & 15) * DHEAD;
    const int q0  = qb * QBLK;
    const int qlo = q0 + wave * 32;      // wave's first q row

    // ---- Q fragments (pre-scaled by 1/8) : qf[m][ks] ----
    bf16x8 qf[2][2];
    #pragma unroll
    for (int m = 0; m < 2; ++m) {
        #pragma unroll
        for (int ks = 0; ks < 2; ++ks) {
            const float* qp = qkv_bh + (size_t)(qlo + m * 16 + l16) * SROW + ks * 32 + lg * 8;
            f32x4 a = *(const f32x4*)qp;
            f32x4 c = *(const f32x4*)(qp + 4);
            bf16x8 v;
            #pragma unroll
            for (int j = 0; j < 4; ++j) { v[j] = f2bf(a[j] * 0.125f); v[4 + j] = f2bf(c[j] * 0.125f); }
            qf[m][ks] = v;
        }
    }

    // ---- flash state ----
    f32x4 o[2][4];
    float m_r[2][4], l_r[2][4];
    #pragma unroll
    for (int m = 0; m < 2; ++m)
        #pragma unroll
        for (int n = 0; n < 4; ++n) o[m][n] = (f32x4){0.f, 0.f, 0.f, 0.f};
    #pragma unroll
    for (int m = 0; m < 2; ++m)
        #pragma unroll
        for (int r = 0; r < 4; ++r) { m_r[m][r] = -1e30f; l_r[m][r] = 0.f; }

    // staging maps
    const int st_kr = tid >> 2;          // K row 0..63
    const int st_kc = (tid & 3) * 16;    // K col base (floats)
    const int st_vp = tid & 31;          // V k-pair (k = 2p, 2p+1)
    const int st_vd = (tid >> 5) * 8;    // V d-base (8 cols)

    f32x4 pk[4], pv[4];                  // prefetch regs

    const int ntiles = (q0 + QBLK) / KVBLK;

    // prologue: load tile 0
    {
        const float* kp = qkv_bh + (size_t)st_kr * SROW + KOFF + st_kc;
        pk[0] = *(const f32x4*)kp;       pk[1] = *(const f32x4*)(kp + 4);
        pk[2] = *(const f32x4*)(kp + 8); pk[3] = *(const f32x4*)(kp + 12);
        const float* vp = qkv_bh + (size_t)(2 * st_vp) * SROW + VOFF + st_vd;
        pv[0] = *(const f32x4*)vp;           pv[1] = *(const f32x4*)(vp + 4);
        pv[2] = *(const f32x4*)(vp + SROW);  pv[3] = *(const f32x4*)(vp + SROW + 4);
    }

    for (int it = 0; it < ntiles; ++it) {
        const int kv0 = it * KVBLK;

        // ---- write staged tile to LDS ----
        {
            bf16x8 w0, w1;
            #pragma unroll
            for (int j = 0; j < 4; ++j) {
                w0[j] = f2bf(pk[0][j]); w0[4 + j] = f2bf(pk[1][j]);
                w1[j] = f2bf(pk[2][j]); w1[4 + j] = f2bf(pk[3][j]);
            }
            *(bf16x8*)&lds_k[st_kr * KP + st_kc]     = w0;
            *(bf16x8*)&lds_k[st_kr * KP + st_kc + 8] = w1;
            #pragma unroll
            for (int i = 0; i < 4; ++i) {
                *(unsigned int*)&lds_vt[(st_vd + i)     * VP + 2 * st_vp] = pack2(pv[0][i], pv[2][i]);
                *(unsigned int*)&lds_vt[(st_vd + 4 + i) * VP + 2 * st_vp] = pack2(pv[1][i], pv[3][i]);
            }
        }
        __syncthreads();

        // ---- issue next tile's global loads (latency hides under compute) ----
        if (it + 1 < ntiles) {
            const int kn = kv0 + KVBLK;
            const float* kp = qkv_bh + (size_t)(kn + st_kr) * SROW + KOFF + st_kc;
            pk[0] = *(const f32x4*)kp;       pk[1] = *(const f32x4*)(kp + 4);
            pk[2] = *(const f32x4*)(kp + 8); pk[3] = *(const f32x4*)(kp + 12);
            const float* vp = qkv_bh + (size_t)(kn + 2 * st_vp) * SROW + VOFF + st_vd;
            pv[0] = *(const f32x4*)vp;           pv[1] = *(const f32x4*)(vp + 4);
            pv[2] = *(const f32x4*)(vp + SROW);  pv[3] = *(const f32x4*)(vp + SROW + 4);
        }

        if (kv0 <= qlo + 31) {
            // ---- S = Q K^T : s[m][c] over 4 col-tiles ----
            f32x4 s[2][4];
            #pragma unroll
            for (int m = 0; m < 2; ++m)
                #pragma unroll
                for (int c = 0; c < 4; ++c) s[m][c] = (f32x4){0.f, 0.f, 0.f, 0.f};
            #pragma unroll
            for (int ks = 0; ks < 2; ++ks) {
                #pragma unroll
                for (int c = 0; c < 4; ++c) {
                    bf16x8 kf = *(const bf16x8*)&lds_k[(c * 16 + l16) * KP + ks * 32 + lg * 8];
                    s[0][c] = __builtin_amdgcn_mfma_f32_16x16x32_bf16(qf[0][ks], kf, s[0][c], 0, 0, 0);
                    s[1][c] = __builtin_amdgcn_mfma_f32_16x16x32_bf16(qf[1][ks], kf, s[1][c], 0, 0, 0);
                }
            }
            // ---- causal mask (D layout: row = m*16+lg*4+r, col = c*16+l16) ----
            if (kv0 + KVBLK - 1 > qlo) {
                #pragma unroll
                for (int m = 0; m < 2; ++m)
                    #pragma unroll
                    for (int r = 0; r < 4; ++r) {
                        const int qg = qlo + m * 16 + lg * 4 + r;
                        #pragma unroll
                        for (int c = 0; c < 4; ++c)
                            if (kv0 + c * 16 + l16 > qg) s[m][c][r] = -1e30f;
                    }
            }
            // ---- online softmax ----
            short* pw = &lds_p[wave * 32 * PP];
            #pragma unroll
            for (int m = 0; m < 2; ++m) {
                #pragma unroll
                for (int r = 0; r < 4; ++r) {
                    float mt = fmaxf(fmaxf(s[m][0][r], s[m][1][r]), fmaxf(s[m][2][r], s[m][3][r]));
                    mt = fmaxf(mt, __shfl_xor(mt, 1));
                    mt = fmaxf(mt, __shfl_xor(mt, 2));
                    mt = fmaxf(mt, __shfl_xor(mt, 4));
                    mt = fmaxf(mt, __shfl_xor(mt, 8));
                    const float mn    = fmaxf(m_r[m][r], mt);
                    const float alpha = __expf(m_r[m][r] - mn);
                    m_r[m][r] = mn;
                    float p0 = __expf(s[m][0][r] - mn);
                    float p1 = __expf(s[m][1][r] - mn);
                    float p2 = __expf(s[m][2][r] - mn);
                    float p3 = __expf(s[m][3][r] - mn);
                    float rs = (p0 + p1) + (p2 + p3);
                    rs += __shfl_xor(rs, 1);
                    rs += __shfl_xor(rs, 2);
                    rs += __shfl_xor(rs, 4);
                    rs += __shfl_xor(rs, 8);
                    l_r[m][r] = l_r[m][r] * alpha + rs;
                    #pragma unroll
                    for (int n = 0; n < 4; ++n) o[m][n][r] *= alpha;
                    const int prow = m * 16 + lg * 4 + r;
                    pw[prow * PP +      l16] = f2bf(p0);
                    pw[prow * PP + 16 + l16] = f2bf(p1);
                    pw[prow * PP + 32 + l16] = f2bf(p2);
                    pw[prow * PP + 48 + l16] = f2bf(p3);
                }
            }
            // wave-local P visibility (writes above, fragment reads below)
            asm volatile("s_waitcnt lgkmcnt(0)" ::: "memory");
            __builtin_amdgcn_sched_barrier(0);
            // ---- O += P V ----
            #pragma unroll
            for (int ks = 0; ks < 2; ++ks) {
                bf16x8 pa0 = *(const bf16x8*)&pw[l16 * PP + ks * 32 + lg * 8];
                bf16x8 pa1 = *(const bf16x8*)&pw[(16 + l16) * PP + ks * 32 + lg * 8];
                #pragma unroll
                for (int n = 0; n < 4; ++n) {
                    bf16x8 vf = *(const bf16x8*)&lds_vt[(n * 16 + l16) * VP + ks * 32 + lg * 8];
                    o[0][n] = __builtin_amdgcn_mfma_f32_16x16x32_bf16(pa0, vf, o[0][n], 0, 0, 0);
                    o[1][n] = __builtin_amdgcn_mfma_f32_16x16x32_bf16(pa1, vf, o[1][n], 0, 0, 0);
                }
            }
        }
        __syncthreads();
    }

    // ---- epilogue: normalize and store (out is (B,H,S,D) f32) ----
    float* outp = out + ((size_t)bh * S_LEN + qlo) * DHEAD;
    #pragma unroll
    for (int m = 0; m < 2; ++m) {
        #pragma unroll
        for (int r = 0; r < 4; ++r) {
            const float inv = 1.0f / l_r[m][r];
            #pragma unroll
            for (int n = 0; n < 4; ++n)
                outp[(m * 16 + lg * 4 + r) * DHEAD + n * 16 + l16] = o[m][n][r] * inv;
        }
    }
}

extern "C" void kernel_launch(void* const* d_in, const int* in_sizes, int n_in,
                              void* d_out, int out_size, void* d_ws, size_t ws_size,
                              hipStream_t stream) {
    const float* qkv = (const float*)d_in[0];
    float* out = (float*)d_out;
    const int nblocks = (S_LEN / QBLK) * 4 * NHEAD;   // 16 * 64 = 1024
    attn_fwd_kernel<<<dim3(nblocks), dim3(256), 0, stream>>>(qkv, out);
}

// Round 3
// 183.417 us; speedup vs baseline: 1.8280x; 1.2761x over previous
//
#include <hip/hip_runtime.h>
#include <hip/hip_bf16.h>

// Causal self-attention forward, B=4 S=2048 H=16 D=64, fp32 in/out, bf16 MFMA.
// qkv: (B,S,3,H,D) f32.  out: (B,H,S,D) f32.
// Round 2: paired causal q-chunks (qb, 31-qb) per block -> uniform work, no tail;
// shared KV staging serves both chunks; P LDS pitch 76 (disjoint bank quarters).

#define S_LEN 2048
#define NHEAD 16
#define DHEAD 64
#define CHUNK 64     // q rows per chunk; each wave owns 16 rows of each chunk
#define KVBLK 64
#define NQB   (S_LEN / CHUNK)   // 32
#define NPAIR (NQB / 2)         // 16
#define SROW  3072   // s-stride in floats = 3*NHEAD*DHEAD
#define KOFF  1024
#define VOFF  2048

#define KP 72   // K LDS pitch (shorts)
#define VP 72   // Vt LDS pitch
#define PP 76   // P LDS pitch (lg-groups land in disjoint bank quarters)

typedef __attribute__((ext_vector_type(8))) short bf16x8;
typedef __attribute__((ext_vector_type(4))) float f32x4;

__device__ __forceinline__ short f2bf(float f) {
    union { __hip_bfloat16 b; short s; } u;
    u.b = __float2bfloat16(f);
    return u.s;
}
__device__ __forceinline__ unsigned int pack2(float lo, float hi) {
    return (unsigned int)(unsigned short)f2bf(lo) | ((unsigned int)(unsigned short)f2bf(hi) << 16);
}

__global__ __launch_bounds__(256)
void attn_fwd_kernel(const float* __restrict__ qkv, float* __restrict__ out)
{
    __shared__ __attribute__((aligned(16))) short lds_k [KVBLK * KP];   // 9.2 KB
    __shared__ __attribute__((aligned(16))) short lds_vt[DHEAD * VP];   // 9.2 KB
    __shared__ __attribute__((aligned(16))) short lds_p [4 * 32 * PP];  // 19.5 KB

    const int tid  = threadIdx.x;
    const int wave = tid >> 6;
    const int lane = tid & 63;
    const int l16  = lane & 15;
    const int lg   = lane >> 4;

    const int bid = blockIdx.x;
    const int pr  = bid & 15;            // pair index: chunk pr (shallow) + chunk 31-pr (deep)
    const int bh  = bid >> 4;            // 0..63

    const float* qkv_bh = qkv + (size_t)(bh >> 4) * (S_LEN * SROW) + (bh & 15) * DHEAD;
    const int qbA = pr;                  // shallow chunk
    const int qbB = NQB - 1 - pr;        // deep chunk
    const int qloA = qbA * CHUNK + wave * 16;   // wave's 16 rows of chunk A
    const int qloB = qbB * CHUNK + wave * 16;

    // ---- Q fragments (pre-scaled by 1/8): qf[m][ks], m=0 -> A, m=1 -> B ----
    bf16x8 qf[2][2];
    #pragma unroll
    for (int m = 0; m < 2; ++m) {
        const int qrow = (m == 0 ? qloA : qloB) + l16;
        #pragma unroll
        for (int ks = 0; ks < 2; ++ks) {
            const float* qp = qkv_bh + (size_t)qrow * SROW + ks * 32 + lg * 8;
            f32x4 a = *(const f32x4*)qp;
            f32x4 c = *(const f32x4*)(qp + 4);
            bf16x8 v;
            #pragma unroll
            for (int j = 0; j < 4; ++j) { v[j] = f2bf(a[j] * 0.125f); v[4 + j] = f2bf(c[j] * 0.125f); }
            qf[m][ks] = v;
        }
    }

    // ---- flash state ----
    f32x4 o[2][4];
    float m_r[2][4], l_r[2][4];
    #pragma unroll
    for (int m = 0; m < 2; ++m)
        #pragma unroll
        for (int n = 0; n < 4; ++n) o[m][n] = (f32x4){0.f, 0.f, 0.f, 0.f};
    #pragma unroll
    for (int m = 0; m < 2; ++m)
        #pragma unroll
        for (int r = 0; r < 4; ++r) { m_r[m][r] = -1e30f; l_r[m][r] = 0.f; }

    // staging maps
    const int st_kr = tid >> 2;          // K row 0..63
    const int st_kc = (tid & 3) * 16;    // K col base (floats)
    const int st_vp = tid & 31;          // V k-pair (k = 2p, 2p+1)
    const int st_vd = (tid >> 5) * 8;    // V d-base (8 cols)

    f32x4 pk[4], pv[4];

    const int ntiles = qbB + 1;

    // prologue: load tile 0
    {
        const float* kp = qkv_bh + (size_t)st_kr * SROW + KOFF + st_kc;
        pk[0] = *(const f32x4*)kp;       pk[1] = *(const f32x4*)(kp + 4);
        pk[2] = *(const f32x4*)(kp + 8); pk[3] = *(const f32x4*)(kp + 12);
        const float* vp = qkv_bh + (size_t)(2 * st_vp) * SROW + VOFF + st_vd;
        pv[0] = *(const f32x4*)vp;           pv[1] = *(const f32x4*)(vp + 4);
        pv[2] = *(const f32x4*)(vp + SROW);  pv[3] = *(const f32x4*)(vp + SROW + 4);
    }

    for (int it = 0; it < ntiles; ++it) {
        const int kv0 = it * KVBLK;

        // ---- write staged tile to LDS ----
        {
            bf16x8 w0, w1;
            #pragma unroll
            for (int j = 0; j < 4; ++j) {
                w0[j] = f2bf(pk[0][j]); w0[4 + j] = f2bf(pk[1][j]);
                w1[j] = f2bf(pk[2][j]); w1[4 + j] = f2bf(pk[3][j]);
            }
            *(bf16x8*)&lds_k[st_kr * KP + st_kc]     = w0;
            *(bf16x8*)&lds_k[st_kr * KP + st_kc + 8] = w1;
            #pragma unroll
            for (int i = 0; i < 4; ++i) {
                *(unsigned int*)&lds_vt[(st_vd + i)     * VP + 2 * st_vp] = pack2(pv[0][i], pv[2][i]);
                *(unsigned int*)&lds_vt[(st_vd + 4 + i) * VP + 2 * st_vp] = pack2(pv[1][i], pv[3][i]);
            }
        }
        __syncthreads();

        // ---- issue next tile's global loads ----
        if (it + 1 < ntiles) {
            const int kn = kv0 + KVBLK;
            const float* kp = qkv_bh + (size_t)(kn + st_kr) * SROW + KOFF + st_kc;
            pk[0] = *(const f32x4*)kp;       pk[1] = *(const f32x4*)(kp + 4);
            pk[2] = *(const f32x4*)(kp + 8); pk[3] = *(const f32x4*)(kp + 12);
            const float* vp = qkv_bh + (size_t)(kn + 2 * st_vp) * SROW + VOFF + st_vd;
            pv[0] = *(const f32x4*)vp;           pv[1] = *(const f32x4*)(vp + 4);
            pv[2] = *(const f32x4*)(vp + SROW);  pv[3] = *(const f32x4*)(vp + SROW + 4);
        }

        // chunk A active for this wave? (B is always active within loop range)
        const bool actA = (kv0 <= qloA + 15);

        // ---- S = Q K^T ----
        f32x4 s[2][4];
        #pragma unroll
        for (int m = 0; m < 2; ++m)
            #pragma unroll
            for (int c = 0; c < 4; ++c) s[m][c] = (f32x4){0.f, 0.f, 0.f, 0.f};
        #pragma unroll
        for (int ks = 0; ks < 2; ++ks) {
            #pragma unroll
            for (int c = 0; c < 4; ++c) {
                bf16x8 kf = *(const bf16x8*)&lds_k[(c * 16 + l16) * KP + ks * 32 + lg * 8];
                s[1][c] = __builtin_amdgcn_mfma_f32_16x16x32_bf16(qf[1][ks], kf, s[1][c], 0, 0, 0);
                if (actA)
                    s[0][c] = __builtin_amdgcn_mfma_f32_16x16x32_bf16(qf[0][ks], kf, s[0][c], 0, 0, 0);
            }
        }

        // ---- mask + online softmax + P writes, per chunk ----
        short* pw = &lds_p[wave * 32 * PP];
        #pragma unroll
        for (int m = 0; m < 2; ++m) {
            if (m == 0 && !actA) continue;
            const int qlo_m = (m == 0) ? qloA : qloB;
            if (kv0 + KVBLK - 1 > qlo_m) {
                #pragma unroll
                for (int r = 0; r < 4; ++r) {
                    const int qg = qlo_m + lg * 4 + r;
                    #pragma unroll
                    for (int c = 0; c < 4; ++c)
                        if (kv0 + c * 16 + l16 > qg) s[m][c][r] = -1e30f;
                }
            }
            #pragma unroll
            for (int r = 0; r < 4; ++r) {
                float mt = fmaxf(fmaxf(s[m][0][r], s[m][1][r]), fmaxf(s[m][2][r], s[m][3][r]));
                mt = fmaxf(mt, __shfl_xor(mt, 1));
                mt = fmaxf(mt, __shfl_xor(mt, 2));
                mt = fmaxf(mt, __shfl_xor(mt, 4));
                mt = fmaxf(mt, __shfl_xor(mt, 8));
                const float mn    = fmaxf(m_r[m][r], mt);
                const float alpha = __expf(m_r[m][r] - mn);
                m_r[m][r] = mn;
                float p0 = __expf(s[m][0][r] - mn);
                float p1 = __expf(s[m][1][r] - mn);
                float p2 = __expf(s[m][2][r] - mn);
                float p3 = __expf(s[m][3][r] - mn);
                float rs = (p0 + p1) + (p2 + p3);
                rs += __shfl_xor(rs, 1);
                rs += __shfl_xor(rs, 2);
                rs += __shfl_xor(rs, 4);
                rs += __shfl_xor(rs, 8);
                l_r[m][r] = l_r[m][r] * alpha + rs;
                #pragma unroll
                for (int n = 0; n < 4; ++n) o[m][n][r] *= alpha;
                const int prow = m * 16 + lg * 4 + r;
                pw[prow * PP +      l16] = f2bf(p0);
                pw[prow * PP + 16 + l16] = f2bf(p1);
                pw[prow * PP + 32 + l16] = f2bf(p2);
                pw[prow * PP + 48 + l16] = f2bf(p3);
            }
        }
        // wave-local P visibility before cross-lane fragment reads
        asm volatile("s_waitcnt lgkmcnt(0)" ::: "memory");
        __builtin_amdgcn_sched_barrier(0);

        // ---- O += P V ----
        #pragma unroll
        for (int ks = 0; ks < 2; ++ks) {
            bf16x8 pa1 = *(const bf16x8*)&pw[(16 + l16) * PP + ks * 32 + lg * 8];
            #pragma unroll
            for (int n = 0; n < 4; ++n) {
                bf16x8 vf = *(const bf16x8*)&lds_vt[(n * 16 + l16) * VP + ks * 32 + lg * 8];
                o[1][n] = __builtin_amdgcn_mfma_f32_16x16x32_bf16(pa1, vf, o[1][n], 0, 0, 0);
            }
            if (actA) {
                bf16x8 pa0 = *(const bf16x8*)&pw[l16 * PP + ks * 32 + lg * 8];
                #pragma unroll
                for (int n = 0; n < 4; ++n) {
                    bf16x8 vf = *(const bf16x8*)&lds_vt[(n * 16 + l16) * VP + ks * 32 + lg * 8];
                    o[0][n] = __builtin_amdgcn_mfma_f32_16x16x32_bf16(pa0, vf, o[0][n], 0, 0, 0);
                }
            }
        }
        __syncthreads();
    }

    // ---- epilogue: normalize and store (out is (B,H,S,D) f32) ----
    #pragma unroll
    for (int m = 0; m < 2; ++m) {
        const int qlo_m = (m == 0) ? qloA : qloB;
        float* outp = out + ((size_t)bh * S_LEN + qlo_m) * DHEAD;
        #pragma unroll
        for (int r = 0; r < 4; ++r) {
            const float inv = 1.0f / l_r[m][r];
            #pragma unroll
            for (int n = 0; n < 4; ++n)
                outp[(lg * 4 + r) * DHEAD + n * 16 + l16] = o[m][n][r] * inv;
        }
    }
}

extern "C" void kernel_launch(void* const* d_in, const int* in_sizes, int n_in,
                              void* d_out, int out_size, void* d_ws, size_t ws_size,
                              hipStream_t stream) {
    const float* qkv = (const float*)d_in[0];
    float* out = (float*)d_out;
    const int nblocks = NPAIR * 4 * NHEAD;   // 16 * 64 = 1024
    attn_fwd_kernel<<<dim3(nblocks), dim3(256), 0, stream>>>(qkv, out);
}